// Round 5
// baseline (562.518 us; speedup 1.0000x reference)
//
#include <hip/hip_runtime.h>
#include <cstddef>

#define T_STEPS 205
#define BATCH   2048
#define NIN     33
#define NRNN    256
#define BB      8           // batch rows per block
#define NTHREADS 256        // 4 waves, 1 per SIMD
#define NTW     4           // n-tiles (16 cols) per wave

// K layout: k = 0..255 -> h[k] (W row 33+k), k = 256..287 -> x[0..31]
// (W rows 0..31), rank-1: x[32] (W row 32) via VALU in the epilogue.
// t-loop has ZERO global loads (R3: in-loop vmcnt retirement serialized each
// step on the previous step's HBM stores).
//
// R5: cut wave-redundant LDS A-reads. All waves read IDENTICAL A fragments,
// so per-CU A-read traffic scales with wave count: 8 waves x 10 b128 = 80
// (~960 cyc, dominant at the ~1760 cyc/step R3 ran at) -> 4 waves x NTW=4
// = 40 b128 (~480 cyc). MFMA issue/SIMD stays 36 x ~4.85 = 175 cyc. The
// NTW=4 + permlane-merge epilogue mapping is harness-verified (R2).
// W frags (36 x half8) live in the unified VGPR/AGPR file; MFMA reads B
// straight from AGPRs.
// R4 lesson: NO DS ops in the pre-barrier shadow (lgkmcnt(0) barrier has no
// counted slack) -> x fragment reads stay at the TOP of the step.

#define A_STRIDE  264       // fp16; row stride 132 dwords == 4 mod 32 banks
#define X_BSTRIDE 32        // fp16 x row: exactly x[0..31]
#define X_TSTRIDE (BB * X_BSTRIDE)   // 256 fp16 per t
#define WS_STRIDE 40        // fp16 elems per W-stage row

typedef _Float16 half8 __attribute__((ext_vector_type(8)));
typedef float    f32x4 __attribute__((ext_vector_type(4)));
typedef unsigned int uintx2 __attribute__((ext_vector_type(2)));

// Barrier that waits ONLY on LDS ops (lgkmcnt), never vmcnt.
__device__ __forceinline__ void lds_barrier() {
    asm volatile("s_waitcnt lgkmcnt(0)\n\ts_barrier" ::: "memory");
}

// result = {a.lanes[0..31], b.lanes[0..31]}
__device__ __forceinline__ float permlane_merge(float a, float b) {
    uintx2 r = __builtin_amdgcn_permlane32_swap(
        __builtin_bit_cast(unsigned int, a),
        __builtin_bit_cast(unsigned int, b), false, false);
    return __builtin_bit_cast(float, r[0]);
}

__device__ __forceinline__ int grow(int kk) {   // gemm-k -> W row
    return (kk < NRNN) ? (33 + kk) : (kk - NRNN);
}

__global__ __launch_bounds__(NTHREADS, 1)
void leaky_rnn_kernel(const float* __restrict__ x,
                      const float* __restrict__ W,
                      const float* __restrict__ bias,
                      const float* __restrict__ h0,
                      float* __restrict__ out)
{
    // A: h only, 8 rows, double-buffered (8.4 KB).
    // X: full x slice fp16 [t][b][32] (105 KB; W-staging aliases its head).
    // X32: x[32] per (t,b) as f32 (6.6 KB).  Total ~120 KB < 160 KB.
    __shared__ __align__(16) _Float16 A_lds[2][8 * A_STRIDE];
    __shared__ __align__(16) _Float16 X_lds[T_STEPS * X_TSTRIDE];
    __shared__ __align__(16) float    X32[T_STEPS * BB];

    const int tid  = threadIdx.x;
    const int lane = tid & 63;
    const int wave = tid >> 6;      // 0..3
    const int q    = lane >> 4;     // quad 0..3
    const int nlo  = lane & 15;
    const int qe   = q & 1;         // post-merge row group: rows qe*4 + r
    const int hi   = lane >> 5;     // 0: even n-tile of pair, 1: odd
    const int b0   = blockIdx.x * BB;

    // ---- one-time: stage W (permuted rows, fp32->fp16), pull B-frags ----
    _Float16* Wst = &X_lds[0];      // dead after init; x preload reuses it
    half8 wfrag[NTW][9];
    {
        const int c = tid;          // 0..255: W column this thread packs
        #pragma unroll
        for (int kt = 0; kt < 9; ++kt) {
            __syncthreads();
            #pragma unroll
            for (int o = 0; o < 4; ++o) {   // k-octet within the 32-row chunk
                half8 pack;
                #pragma unroll
                for (int i = 0; i < 8; ++i)
                    pack[i] = (_Float16)W[grow(kt * 32 + o * 8 + i) * NRNN + c];
                *(half8*)&Wst[c * WS_STRIDE + o * 8] = pack;
            }
            __syncthreads();
            #pragma unroll
            for (int nt = 0; nt < NTW; ++nt) {
                int n = wave * 64 + nt * 16 + nlo;
                wfrag[nt][kt] = *(const half8*)&Wst[n * WS_STRIDE + q * 8];
            }
        }
        __syncthreads();   // all frag reads done before x preload clobbers Wst
    }

    // per-lane epilogue constants (post-merge layout): pair p2 in {0,1}
    int ecol[2]; float bve[2]; float w32e[2];
    #pragma unroll
    for (int p2 = 0; p2 < 2; ++p2) {
        ecol[p2] = wave * 64 + (2 * p2 + hi) * 16 + nlo;   // 0..255
        bve[p2]  = bias[ecol[p2]];
        w32e[p2] = W[32 * NRNN + ecol[p2]];                // rank-1 row (x[32])
    }

    // ---- preload ALL x for this block: fp32 global -> LDS (float4 loads) ----
    // per-t slice is 264 contiguous floats = 66 float4, 16B-aligned.
    for (int e = tid; e < T_STEPS * 66; e += NTHREADS) {
        int t  = e / 66;
        int r4 = e - t * 66;
        f32x4 v = *(const f32x4*)&x[((size_t)t * BATCH + b0) * NIN + r4 * 4];
        #pragma unroll
        for (int j = 0; j < 4; ++j) {
            int idx = r4 * 4 + j;        // 0..263 within the slice
            int b   = idx / 33;
            int xi  = idx - b * 33;
            if (xi < 32) X_lds[t * X_TSTRIDE + b * X_BSTRIDE + xi] = (_Float16)v[j];
            else         X32[t * BB + b] = v[j];
        }
    }

    // ---- h0 -> A buf0 + registers ----
    float hreg[2][4];
    #pragma unroll
    for (int p2 = 0; p2 < 2; ++p2)
        #pragma unroll
        for (int r = 0; r < 4; ++r) {
            int b = qe * 4 + r;
            float h = h0[(b0 + b) * NRNN + ecol[p2]];
            hreg[p2][r] = h;
            A_lds[0][b * A_STRIDE + ecol[p2]] = (_Float16)h;
        }
    __syncthreads();   // end of init

    const int am = nlo & 7;   // broadcast: lanes 8..15 mirror 0..7 (rows 8..15 unused)
    int p = 0;
    for (int t = 0; t < T_STEPS; ++t) {
        const _Float16* __restrict__ Ar = A_lds[p];
        _Float16* __restrict__ Aw = A_lds[p ^ 1];
        const _Float16* __restrict__ Xt = &X_lds[t * X_TSTRIDE];

        // x fragments: issued first (post-barrier), consumed last -> latency hides
        half8 xf   = *(const half8*)&Xt[am * X_BSTRIDE + q * 8];
        f32x4 x32v = *(const f32x4*)&X32[t * BB + qe * 4];

        // split-K accumulators: 8 independent MFMA chains per wave
        f32x4 acc[NTW][2];
        #pragma unroll
        for (int nt = 0; nt < NTW; ++nt)
            #pragma unroll
            for (int s = 0; s < 2; ++s) acc[nt][s] = (f32x4){0.f, 0.f, 0.f, 0.f};

        #pragma unroll
        for (int kt = 0; kt < 8; ++kt) {
            half8 af = *(const half8*)&Ar[am * A_STRIDE + kt * 32 + q * 8];
            #pragma unroll
            for (int nt = 0; nt < NTW; ++nt)
                acc[nt][kt & 1] = __builtin_amdgcn_mfma_f32_16x16x32_f16(af, wfrag[nt][kt], acc[nt][kt & 1], 0, 0, 0);
        }
        #pragma unroll
        for (int nt = 0; nt < NTW; ++nt)
            acc[nt][0] = __builtin_amdgcn_mfma_f32_16x16x32_f16(xf, wfrag[nt][8], acc[nt][0], 0, 0, 0);

        f32x4 s[NTW];
        #pragma unroll
        for (int nt = 0; nt < NTW; ++nt) s[nt] = acc[nt][0] + acc[nt][1];

        // merge n-tile pairs across lane halves; epilogue on ALL 64 lanes.
        float hn_[2][4];
        #pragma unroll
        for (int p2 = 0; p2 < 2; ++p2)
            #pragma unroll
            for (int r = 0; r < 4; ++r) {
                float m   = permlane_merge(s[2 * p2][r], s[2 * p2 + 1][r]);
                float pre = m + bve[p2] + x32v[r] * w32e[p2];
                float hn  = 0.8f * hreg[p2][r] + 0.2f * fmaxf(pre, 0.f);
                hreg[p2][r] = hn;
                hn_[p2][r]  = hn;
                Aw[(qe * 4 + r) * A_STRIDE + ecol[p2]] = (_Float16)hn;  // LDS first
            }

        #pragma unroll
        for (int p2 = 0; p2 < 2; ++p2) {
            float* op = out + ((size_t)t * BATCH + b0 + qe * 4) * NRNN + ecol[p2];
            #pragma unroll
            for (int r = 0; r < 4; ++r)                                  // then HBM
                __builtin_nontemporal_store(hn_[p2][r], op + (size_t)r * NRNN);
        }

        lds_barrier();   // lgkmcnt only; stores are never waited on
        p ^= 1;
    }
}

extern "C" void kernel_launch(void* const* d_in, const int* in_sizes, int n_in,
                              void* d_out, int out_size, void* d_ws, size_t ws_size,
                              hipStream_t stream) {
    const float* x    = (const float*)d_in[0];
    const float* W    = (const float*)d_in[1];   // (289, 256) row-major
    const float* bias = (const float*)d_in[2];
    const float* h0   = (const float*)d_in[3];
    float* out = (float*)d_out;

    dim3 grid(BATCH / BB);      // 256 blocks -> 1 per CU
    dim3 block(NTHREADS);       // 4 waves
    leaky_rnn_kernel<<<grid, block, 0, stream>>>(x, W, bias, h0, out);
}

// Round 6
// 558.523 us; speedup vs baseline: 1.0072x; 1.0072x over previous
//
#include <hip/hip_runtime.h>
#include <cstddef>

#define T_STEPS 205
#define BATCH   2048
#define NIN     33
#define NRNN    256
#define BB      4           // batch rows per block
#define NTHREADS 256        // 4 waves, 1 per SIMD *per block*
#define NTW     4           // n-tiles (16 cols) per wave

// K layout: k = 0..255 -> h[k] (W row 33+k), k = 256..287 -> x[0..31]
// (W rows 0..31), rank-1: x[32] (W row 32) via VALU in the epilogue.
// t-loop has ZERO global loads (R3: in-loop vmcnt retirement serialized each
// step on the previous step's HBM stores).
//
// R6: TWO INDEPENDENT BLOCKS PER CU. R5 falsified the LDS-redundancy theory
// (halving A-reads at 1 wave/SIMD was SLOWER than R3's 8-wave 2/SIMD):
// the step is latency/convergence-bound, and co-resident waves are what
// hide it. R3's single barrier domain still exposes convergence: all 8
// waves wait on the slowest. Here each CU hosts 2 blocks (BB=4, grid 512,
// ~60 KB LDS each) whose barriers are INDEPENDENT -> while block A's waves
// sit in lgkmcnt(0)+s_barrier, block B's waves keep issuing. Per-CU LDS
// traffic equals R3 (2 x 36 b128 A-reads); MFMA issue ~350 cyc/SIMD, ample.
// BB=4 merge: permlane16_swap pairs + permlane32_swap put acc[q]'s valid
// rows 0..3 into lane-quad q -> all 64 lanes epilogue-active, 1 col/lane.

#define A_STRIDE  264       // fp16; row stride 132 dwords == 4 mod 32 banks
#define X_BSTRIDE 32        // fp16 x row: exactly x[0..31]
#define X_TSTRIDE (BB * X_BSTRIDE)   // 128 fp16 per t
#define WS_STRIDE 40        // fp16 elems per W-stage row

typedef _Float16 half8 __attribute__((ext_vector_type(8)));
typedef float    f32x4 __attribute__((ext_vector_type(4)));
typedef unsigned int uintx2 __attribute__((ext_vector_type(2)));

// Barrier that waits ONLY on LDS ops (lgkmcnt), never vmcnt.
__device__ __forceinline__ void lds_barrier() {
    asm volatile("s_waitcnt lgkmcnt(0)\n\ts_barrier" ::: "memory");
}

// 4-way merge: lane-quad q receives acc[q]'s lanes 0..15 (valid C rows 0..3).
//  p16_swap(a,b)[0] = {a.l0-15,  b.l0-15,  a.l32-47, b.l32-47}
//  p32_swap(a,b)[0] = {a.l0-31,  b.l0-31}
//  => r = {a0.q0, a1.q0, a2.q0, a3.q0}
__device__ __forceinline__ float merge4(float a0, float a1, float a2, float a3) {
    uintx2 t0 = __builtin_amdgcn_permlane16_swap(
        __builtin_bit_cast(unsigned int, a0),
        __builtin_bit_cast(unsigned int, a1), false, false);
    uintx2 t1 = __builtin_amdgcn_permlane16_swap(
        __builtin_bit_cast(unsigned int, a2),
        __builtin_bit_cast(unsigned int, a3), false, false);
    uintx2 r  = __builtin_amdgcn_permlane32_swap(t0[0], t1[0], false, false);
    return __builtin_bit_cast(float, r[0]);
}

__device__ __forceinline__ int grow(int kk) {   // gemm-k -> W row
    return (kk < NRNN) ? (33 + kk) : (kk - NRNN);
}

__global__ __launch_bounds__(NTHREADS, 2)
void leaky_rnn_kernel(const float* __restrict__ x,
                      const float* __restrict__ W,
                      const float* __restrict__ bias,
                      const float* __restrict__ h0,
                      float* __restrict__ out)
{
    // A: h only, 4 rows, double-buffered (4.2 KB).
    // X: x slice fp16 [t][b][32] (52.5 KB; W-staging aliases its head, 20.5 KB).
    // X32: x[32] per (t,b) as f32 (3.3 KB).  Total ~60 KB -> 2 blocks/CU.
    __shared__ __align__(16) _Float16 A_lds[2][BB * A_STRIDE];
    __shared__ __align__(16) _Float16 X_lds[T_STEPS * X_TSTRIDE];
    __shared__ __align__(16) float    X32[T_STEPS * BB];

    const int tid  = threadIdx.x;
    const int lane = tid & 63;
    const int wave = tid >> 6;      // 0..3
    const int q    = lane >> 4;     // quad 0..3
    const int nlo  = lane & 15;
    const int b0   = blockIdx.x * BB;

    // ---- one-time: stage W (permuted rows, fp32->fp16), pull B-frags ----
    _Float16* Wst = &X_lds[0];      // dead after init; x preload reuses it
    half8 wfrag[NTW][9];
    {
        const int c = tid;          // 0..255: W column this thread packs
        #pragma unroll
        for (int kt = 0; kt < 9; ++kt) {
            __syncthreads();
            #pragma unroll
            for (int o = 0; o < 4; ++o) {   // k-octet within the 32-row chunk
                half8 pack;
                #pragma unroll
                for (int i = 0; i < 8; ++i)
                    pack[i] = (_Float16)W[grow(kt * 32 + o * 8 + i) * NRNN + c];
                *(half8*)&Wst[c * WS_STRIDE + o * 8] = pack;
            }
            __syncthreads();
            #pragma unroll
            for (int nt = 0; nt < NTW; ++nt) {
                int n = wave * 64 + nt * 16 + nlo;
                wfrag[nt][kt] = *(const half8*)&Wst[n * WS_STRIDE + q * 8];
            }
        }
        __syncthreads();   // all frag reads done before x preload clobbers Wst
    }

    // per-lane epilogue constants (post-merge4 layout): ONE column per lane
    const int   ecol = wave * 64 + q * 16 + nlo;   // 0..255
    const float bve  = bias[ecol];
    const float w32e = W[32 * NRNN + ecol];        // rank-1 row (x[32])

    // ---- preload ALL x for this block: fp32 global -> LDS (float4 loads) ----
    // per-t slice is BB*NIN = 132 contiguous floats = 33 float4, 16B-aligned
    // (base offset (t*BATCH+b0)*33 floats; 2048*33 and 4*33 both x16B).
    for (int e = tid; e < T_STEPS * 33; e += NTHREADS) {
        int t  = e / 33;
        int r4 = e - t * 33;
        f32x4 v = *(const f32x4*)&x[((size_t)t * BATCH + b0) * NIN + r4 * 4];
        #pragma unroll
        for (int j = 0; j < 4; ++j) {
            int idx = r4 * 4 + j;        // 0..131 within the slice
            int b   = idx / 33;
            int xi  = idx - b * 33;
            if (xi < 32) X_lds[t * X_TSTRIDE + b * X_BSTRIDE + xi] = (_Float16)v[j];
            else         X32[t * BB + b] = v[j];
        }
    }

    // ---- h0 -> A buf0 + registers (4 rows, 1 col per lane) ----
    float hreg[4];
    #pragma unroll
    for (int r = 0; r < 4; ++r) {
        float h = h0[(b0 + r) * NRNN + ecol];
        hreg[r] = h;
        A_lds[0][r * A_STRIDE + ecol] = (_Float16)h;
    }
    __syncthreads();   // end of init

    const int am = lane & 3;  // broadcast: all lanes mirror rows 0..3 (C rows 4..15 unused)
    int p = 0;
    for (int t = 0; t < T_STEPS; ++t) {
        const _Float16* __restrict__ Ar = A_lds[p];
        _Float16* __restrict__ Aw = A_lds[p ^ 1];
        const _Float16* __restrict__ Xt = &X_lds[t * X_TSTRIDE];

        // x fragments: issued first (post-barrier), consumed last -> latency hides
        half8 xf   = *(const half8*)&Xt[am * X_BSTRIDE + q * 8];
        f32x4 x32v = *(const f32x4*)&X32[t * BB];     // all 4 batches, broadcast

        // split-K accumulators: 8 independent MFMA chains per wave
        f32x4 acc[NTW][2];
        #pragma unroll
        for (int nt = 0; nt < NTW; ++nt)
            #pragma unroll
            for (int s = 0; s < 2; ++s) acc[nt][s] = (f32x4){0.f, 0.f, 0.f, 0.f};

        #pragma unroll
        for (int kt = 0; kt < 8; ++kt) {
            half8 af = *(const half8*)&Ar[am * A_STRIDE + kt * 32 + q * 8];
            #pragma unroll
            for (int nt = 0; nt < NTW; ++nt)
                acc[nt][kt & 1] = __builtin_amdgcn_mfma_f32_16x16x32_f16(af, wfrag[nt][kt], acc[nt][kt & 1], 0, 0, 0);
        }
        #pragma unroll
        for (int nt = 0; nt < NTW; ++nt)
            acc[nt][0] = __builtin_amdgcn_mfma_f32_16x16x32_f16(xf, wfrag[nt][8], acc[nt][0], 0, 0, 0);

        f32x4 s[NTW];
        #pragma unroll
        for (int nt = 0; nt < NTW; ++nt) s[nt] = acc[nt][0] + acc[nt][1];

        // merge all 4 n-tiles: lane-quad q <- acc[q] rows 0..3 of col nlo.
        float hn_[4];
        #pragma unroll
        for (int r = 0; r < 4; ++r) {
            float m   = merge4(s[0][r], s[1][r], s[2][r], s[3][r]);
            float pre = m + bve + x32v[r] * w32e;
            float hn  = 0.8f * hreg[r] + 0.2f * fmaxf(pre, 0.f);
            hreg[r] = hn;
            hn_[r]  = hn;
            Aw[r * A_STRIDE + ecol] = (_Float16)hn;   // LDS first
        }

        float* op = out + ((size_t)t * BATCH + b0) * NRNN + ecol;
        #pragma unroll
        for (int r = 0; r < 4; ++r)                    // then HBM (coalesced/wave)
            __builtin_nontemporal_store(hn_[r], op + (size_t)r * NRNN);

        lds_barrier();   // lgkmcnt only; stores are never waited on
        p ^= 1;
    }
}

extern "C" void kernel_launch(void* const* d_in, const int* in_sizes, int n_in,
                              void* d_out, int out_size, void* d_ws, size_t ws_size,
                              hipStream_t stream) {
    const float* x    = (const float*)d_in[0];
    const float* W    = (const float*)d_in[1];   // (289, 256) row-major
    const float* bias = (const float*)d_in[2];
    const float* h0   = (const float*)d_in[3];
    float* out = (float*)d_out;

    dim3 grid(BATCH / BB);      // 512 blocks -> 2 per CU (independent barriers)
    dim3 block(NTHREADS);       // 4 waves
    leaky_rnn_kernel<<<grid, block, 0, stream>>>(x, W, bias, h0, out);
}